// Round 8
// baseline (428.683 us; speedup 1.0000x reference)
//
#include <hip/hip_runtime.h>

// Problem constants (fixed by the reference setup)
#define NN 100000          // N_NODES
#define NE 1600000         // N_EDGES
#define IND 128            // IN_DIM
#define FD 32              // OUT_DIM
#define NH 8               // HEADS
#define HF 256             // NH*FD
#define ETOT 1700000       // NE + NN self loops
#define NB 391             // ceil(NN/256) scan blocks
#define GB 1563            // gemm blocks (ceil(NN/64))
#define HB 6641            // hist/scatter blocks (ceil(ETOT/256))

typedef __attribute__((ext_vector_type(8))) short bfrag;    // 8 bf16 (4 VGPRs)
typedef __attribute__((ext_vector_type(4))) float ffrag;    // 4 fp32 acc

// bf16 helpers (RNE), bit-level to avoid header variance
static __device__ __forceinline__ unsigned short f2bf(float f) {
  union { float f; unsigned u; } v; v.f = f;
  unsigned r = v.u + 0x7FFF + ((v.u >> 16) & 1);
  return (unsigned short)(r >> 16);
}
static __device__ __forceinline__ float bf2f(unsigned short u) {
  union { unsigned u; float f; } v; v.u = ((unsigned)u) << 16;
  return v.f;
}

// ---------------------------------------------------------------------------
// K0: pack W^T in bf16: Wt[c*128 + k] = bf16(W[k*256 + c]).
// A-operand fragment for feature c is then 16B contiguous at Wt+c*128+kt*32+q*8.
// ---------------------------------------------------------------------------
__global__ __launch_bounds__(256) void k_convW(const float* __restrict__ W,
                                               unsigned short* __restrict__ Wt) {
  int tid = blockIdx.x * 256 + threadIdx.x;   // 32768 threads
  int c = tid >> 7, k = tid & 127;
  Wt[tid] = f2bf(W[k * HF + c]);
}

// ---------------------------------------------------------------------------
// K1: operand-swapped MFMA projection GEMM + in-register logits.
// D = Wt_frag (A) x X_frag (B) => D[feature][node] = h^T tile.
// C/D layout col=lane&15 -> NODE, row=quad*4+r -> FEATURE: each lane holds
// 4 consecutive features of ONE node => direct 8-B bf16 store, NO transpose,
// no epilogue LDS, no extra syncthreads (R7 post-mortem: the transpose
// epilogue + branch-fused histogram destroyed occupancy).
// Logits: per-lane dot of acc with att vectors (fp32-exact), quad-reduce
// via shfl_xor(16|32), 16-B coalesced stores from quad 0.
// ---------------------------------------------------------------------------
__global__ __launch_bounds__(256) void k_gemm(const float* __restrict__ X,
                                              const unsigned short* __restrict__ Wt,
                                              const float* __restrict__ att_src,
                                              const float* __restrict__ att_dst,
                                              unsigned short* __restrict__ HhB,
                                              float* __restrict__ AS,
                                              float* __restrict__ AD) {
  __shared__ __align__(16) unsigned short Xs[64 * 136];   // 17408 B
  const int n0 = blockIdx.x * 64;
  const int t = threadIdx.x;

  // stage X tile fp32 -> bf16 LDS (stride 136 ushorts)
#pragma unroll
  for (int j = 0; j < 8; ++j) {
    int g = t + j * 256;            // float4-group id, 0..2047
    int r = g >> 5, c4 = g & 31;
    int gr = n0 + r; if (gr >= NN) gr = NN - 1;   // tail clamp (unused values)
    float4 x = *(const float4*)(X + (size_t)gr * IND + c4 * 4);
    ushort4 u;
    u.x = f2bf(x.x); u.y = f2bf(x.y); u.z = f2bf(x.z); u.w = f2bf(x.w);
    *(ushort4*)(Xs + r * 136 + c4 * 4) = u;
  }
  __syncthreads();

  const int w = t >> 6, lane = t & 63;
  const int quad = lane >> 4, m = lane & 15;
  const int rb = w * 16;
  const int node = n0 + rb + m;     // this lane's node (D column)

  // B operand: X fragment, B[k][n=m] = X[node][k], 16B contiguous in k
  bfrag xfr[4];
#pragma unroll
  for (int kt = 0; kt < 4; ++kt)
    xfr[kt] = *(const bfrag*)(Xs + (rb + m) * 136 + kt * 32 + quad * 8);

  ffrag acc[16];
#pragma unroll
  for (int ct = 0; ct < 16; ++ct) {
    ffrag c = {0.f, 0.f, 0.f, 0.f};
#pragma unroll
    for (int kt = 0; kt < 4; ++kt) {
      // A operand: Wt fragment, A[m'=feature ct*16+m][k], 16B contiguous
      bfrag a = *(const bfrag*)(Wt + (ct * 16 + m) * IND + kt * 32 + quad * 8);
      c = __builtin_amdgcn_mfma_f32_16x16x32_bf16(a, xfr[kt], c, 0, 0, 0);
    }
    acc[ct] = c;
  }

  // logits from fp32 accumulators (exact); lane covers features
  // ct*16+quad*4+r across its 16 tiles
  float ss[8], dd[8];
#pragma unroll
  for (int hh = 0; hh < NH; ++hh) {
    float s = 0.f, d = 0.f;
#pragma unroll
    for (int half = 0; half < 2; ++half) {
      int ct = hh * 2 + half;
      float4 as = *(const float4*)(att_src + ct * 16 + quad * 4);
      float4 ad = *(const float4*)(att_dst + ct * 16 + quad * 4);
      ffrag c = acc[ct];
      s += c[0] * as.x + c[1] * as.y + c[2] * as.z + c[3] * as.w;
      d += c[0] * ad.x + c[1] * ad.y + c[2] * ad.z + c[3] * ad.w;
    }
    // reduce over the 4 quads holding the same node (lanes differ in bits 4,5)
    s += __shfl_xor(s, 16, 64); s += __shfl_xor(s, 32, 64);
    d += __shfl_xor(d, 16, 64); d += __shfl_xor(d, 32, 64);
    ss[hh] = s; dd[hh] = d;
  }

  if (node < NN) {
    // h store: 16 x 8B per lane, node-row fully covered by its 4 quads
#pragma unroll
    for (int ct = 0; ct < 16; ++ct) {
      ushort4 u;
      u.x = f2bf(acc[ct][0]); u.y = f2bf(acc[ct][1]);
      u.z = f2bf(acc[ct][2]); u.w = f2bf(acc[ct][3]);
      *(ushort4*)(HhB + (size_t)node * HF + ct * 16 + quad * 4) = u;
    }
    if (quad == 0) {                 // one lane per node writes the logits
      float4 v0 = {ss[0], ss[1], ss[2], ss[3]};
      float4 v1 = {ss[4], ss[5], ss[6], ss[7]};
      *(float4*)(AS + node * NH)     = v0;
      *(float4*)(AS + node * NH + 4) = v1;
      float4 w0 = {dd[0], dd[1], dd[2], dd[3]};
      float4 w1 = {dd[4], dd[5], dd[6], dd[7]};
      *(float4*)(AD + node * NH)     = w0;
      *(float4*)(AD + node * NH + 4) = w1;
    }
  }
}

// ---------------------------------------------------------------------------
// K2: dst histogram + per-edge rank (standalone again: zero LDS, full
// occupancy — R7 lesson: branch-fusion imposed the GEMM's LDS limit on it)
// ---------------------------------------------------------------------------
__global__ __launch_bounds__(256) void k_hist(const int* __restrict__ ei,
                                              int* __restrict__ cnt,
                                              int* __restrict__ re) {
  int e = blockIdx.x * 256 + threadIdx.x;
  if (e >= ETOT) return;
  int d = (e < NE) ? ei[NE + e] : (e - NE);
  re[e] = atomicAdd(&cnt[d], 1);
}

// ---------------------------------------------------------------------------
// CSR: 2-level exclusive scan + atomic-free scatter
// ---------------------------------------------------------------------------
__global__ __launch_bounds__(256) void k_scan1(const int* __restrict__ cnt,
                                               int* __restrict__ lpre,
                                               int* __restrict__ bsum) {
  __shared__ int sd[256];
  int t = threadIdx.x, i = blockIdx.x * 256 + t;
  int v = (i < NN) ? cnt[i] : 0;
  sd[t] = v; __syncthreads();
  for (int off = 1; off < 256; off <<= 1) {
    int x = (t >= off) ? sd[t - off] : 0;
    __syncthreads();
    sd[t] += x;
    __syncthreads();
  }
  if (i < NN) lpre[i] = sd[t] - v;
  if (t == 255) bsum[blockIdx.x] = sd[255];
}

__global__ __launch_bounds__(512) void k_scan2(const int* __restrict__ bsum,
                                               int* __restrict__ boff) {
  __shared__ int sd[512];
  int t = threadIdx.x;
  int v = (t < NB) ? bsum[t] : 0;
  sd[t] = v; __syncthreads();
  for (int off = 1; off < 512; off <<= 1) {
    int x = (t >= off) ? sd[t - off] : 0;
    __syncthreads();
    sd[t] += x;
    __syncthreads();
  }
  if (t < NB) boff[t] = sd[t] - v;
}

__global__ __launch_bounds__(256) void k_scan3(const int* __restrict__ lpre,
                                               const int* __restrict__ boff,
                                               int* __restrict__ rowptr) {
  int i = blockIdx.x * 256 + threadIdx.x;
  if (i < NN) rowptr[i] = boff[blockIdx.x] + lpre[i];
  if (i == 0) rowptr[NN] = ETOT;
}

__global__ __launch_bounds__(256) void k_scatter(const int* __restrict__ ei,
                                                 const int* __restrict__ rowptr,
                                                 const int* __restrict__ re,
                                                 int* __restrict__ csr) {
  int e = blockIdx.x * 256 + threadIdx.x;
  if (e >= ETOT) return;
  int s, d;
  if (e < NE) { s = ei[e]; d = ei[NE + e]; } else { s = d = e - NE; }
  csr[rowptr[d] + re[e]] = s;      // rank precomputed: no atomics
}

// ---------------------------------------------------------------------------
// K3: single-pass GAT aggregation (unchanged — at the delivered-BW wall:
// 870 MB logical gather / 138 us ≈ 6.3 TB/s). One wave per dst node.
// ---------------------------------------------------------------------------
__global__ __launch_bounds__(256) void k_gat(const int* __restrict__ rowptr,
                                             const int* __restrict__ csr,
                                             const float* __restrict__ AS,
                                             const float* __restrict__ AD,
                                             const unsigned short* __restrict__ HhB,
                                             const float* __restrict__ bias,
                                             float* __restrict__ out) {
  const int d = blockIdx.x * 4 + (threadIdx.x >> 6);   // 25000*4 == NN exactly
  const int lane = threadIdx.x & 63;
  const int hh = lane >> 3, sub = lane & 7;
  const int start = rowptr[d], end = rowptr[d + 1];
  const float ad = AD[d * NH + hh];

  float den = 0.f, a0 = 0.f, a1 = 0.f, a2 = 0.f, a3 = 0.f;

  for (int base = start; base < end; base += 64) {
    int srcs = 0;
    if (base + lane < end) srcs = csr[base + lane];
    int m = end - base; if (m > 64) m = 64;
    int t = 0;
    for (; t + 1 < m; t += 2) {               // 2-way unroll for load ILP
      int s0 = __shfl(srcs, t, 64);
      int s1 = __shfl(srcs, t + 1, 64);
      float lg0 = AS[s0 * NH + hh] + ad;
      float lg1 = AS[s1 * NH + hh] + ad;
      ushort4 h0 = *(const ushort4*)(HhB + (size_t)s0 * HF + hh * 32 + sub * 4);
      ushort4 h1 = *(const ushort4*)(HhB + (size_t)s1 * HF + hh * 32 + sub * 4);
      lg0 = lg0 > 0.f ? lg0 : 0.2f * lg0;
      lg1 = lg1 > 0.f ? lg1 : 0.2f * lg1;
      float e0 = __expf(lg0), e1 = __expf(lg1);
      den += e0 + e1;
      a0 += e0 * bf2f(h0.x) + e1 * bf2f(h1.x);
      a1 += e0 * bf2f(h0.y) + e1 * bf2f(h1.y);
      a2 += e0 * bf2f(h0.z) + e1 * bf2f(h1.z);
      a3 += e0 * bf2f(h0.w) + e1 * bf2f(h1.w);
    }
    if (t < m) {
      int s0 = __shfl(srcs, t, 64);
      float lg0 = AS[s0 * NH + hh] + ad;
      ushort4 h0 = *(const ushort4*)(HhB + (size_t)s0 * HF + hh * 32 + sub * 4);
      lg0 = lg0 > 0.f ? lg0 : 0.2f * lg0;
      float e0 = __expf(lg0);
      den += e0;
      a0 += e0 * bf2f(h0.x); a1 += e0 * bf2f(h0.y);
      a2 += e0 * bf2f(h0.z); a3 += e0 * bf2f(h0.w);
    }
  }

  const float inv = 1.f / (den + 1e-16f);
  a0 *= inv; a1 *= inv; a2 *= inv; a3 *= inv;

#pragma unroll
  for (int off = 8; off < 64; off <<= 1) {    // sum over the 8 heads
    a0 += __shfl_xor(a0, off, 64);
    a1 += __shfl_xor(a1, off, 64);
    a2 += __shfl_xor(a2, off, 64);
    a3 += __shfl_xor(a3, off, 64);
  }

  if (lane < 8) {
    float4 o;
    o.x = a0 * 0.125f + bias[sub * 4 + 0];
    o.y = a1 * 0.125f + bias[sub * 4 + 1];
    o.z = a2 * 0.125f + bias[sub * 4 + 2];
    o.w = a3 * 0.125f + bias[sub * 4 + 3];
    *(float4*)(out + (size_t)d * FD + sub * 4) = o;
  }
}

// ---------------------------------------------------------------------------
// Workspace layout:
//   HhB    bf16[N*256]            floats [0,          12,800,000)   51.2 MB
//   AS     float[N*8]                    [12,800,000, 13,600,000)    3.2 MB
//   AD     float[N*8]                    [13,600,000, 14,400,000)    3.2 MB
//   ints (base = ws + 14,400,000):
//     cnt    [0,         100,000)
//     lpre   [100,000,   200,000)
//     bsum   [200,000,   200,512)
//     boff   [200,512,   201,024)
//     rowptr [201,024,   301,056)
//     re     [301,056,   2,001,056)   per-edge rank, 6.8 MB
//     csr    [2,001,056, 3,701,056)   8.4 MB
//     Wt     [3,701,056, 3,717,440)   32768 bf16 (W^T)
// ---------------------------------------------------------------------------
extern "C" void kernel_launch(void* const* d_in, const int* in_sizes, int n_in,
                              void* d_out, int out_size, void* d_ws, size_t ws_size,
                              hipStream_t stream) {
  const float* X       = (const float*)d_in[0];
  const int*   ei      = (const int*)d_in[1];
  const float* W       = (const float*)d_in[2];
  const float* att_src = (const float*)d_in[3];
  const float* att_dst = (const float*)d_in[4];
  const float* bias    = (const float*)d_in[5];
  float* out = (float*)d_out;
  float* ws  = (float*)d_ws;

  unsigned short* HhB = (unsigned short*)ws;
  float* AS = ws + 12800000;
  float* AD = ws + 13600000;
  int* ib     = (int*)(ws + 14400000);
  int* cnt    = ib;
  int* lpre   = ib + 100000;
  int* bsum   = ib + 200000;
  int* boff   = ib + 200512;
  int* rowptr = ib + 201024;
  int* re     = ib + 301056;
  int* csr    = ib + 2001056;
  unsigned short* Wt = (unsigned short*)(ib + 3701056);

  hipMemsetAsync(cnt, 0, (size_t)NN * sizeof(int), stream);

  k_convW  <<<128, 256, 0, stream>>>(W, Wt);
  k_gemm   <<<GB, 256, 0, stream>>>(X, Wt, att_src, att_dst, HhB, AS, AD);
  k_hist   <<<HB, 256, 0, stream>>>(ei, cnt, re);
  k_scan1  <<<NB, 256, 0, stream>>>(cnt, lpre, bsum);
  k_scan2  <<<1, 512, 0, stream>>>(bsum, boff);
  k_scan3  <<<NB, 256, 0, stream>>>(lpre, boff, rowptr);
  k_scatter<<<HB, 256, 0, stream>>>(ei, rowptr, re, csr);
  k_gat    <<<NN / 4, 256, 0, stream>>>(rowptr, csr, AS, AD, HhB, bias, out);
}

// Round 9
// 407.824 us; speedup vs baseline: 1.0511x; 1.0511x over previous
//
#include <hip/hip_runtime.h>

// Problem constants (fixed by the reference setup)
#define NN 100000          // N_NODES
#define NE 1600000         // N_EDGES
#define IND 128            // IN_DIM
#define FD 32              // OUT_DIM
#define NH 8               // HEADS
#define HF 256             // NH*FD
#define ETOT 1700000       // NE + NN self loops
#define GB 1563            // gemm blocks (ceil(NN/64))

// CSR-build split parameters (R8 post-mortem: global-atomic passes cost
// 100-140 us each; this build uses LDS-only atomics)
#define NBKT 782           // dst buckets = ceil(NN/128), bucket = d>>7
#define EPB  16384         // edges per partition block
#define NP   104           // partition blocks = ceil(ETOT/EPB)
#define CAP  3072          // bucket staging capacity (mean 2176, sigma ~46)

typedef __attribute__((ext_vector_type(8))) short bfrag;    // 8 bf16 (4 VGPRs)
typedef __attribute__((ext_vector_type(4))) float ffrag;    // 4 fp32 acc

// bf16 helpers (RNE), bit-level to avoid header variance
static __device__ __forceinline__ unsigned short f2bf(float f) {
  union { float f; unsigned u; } v; v.f = f;
  unsigned r = v.u + 0x7FFF + ((v.u >> 16) & 1);
  return (unsigned short)(r >> 16);
}
static __device__ __forceinline__ float bf2f(unsigned short u) {
  union { unsigned u; float f; } v; v.u = ((unsigned)u) << 16;
  return v.f;
}

// ---------------------------------------------------------------------------
// K0: pack W^T in bf16: Wt[c*128 + k] = bf16(W[k*256 + c]).
// ---------------------------------------------------------------------------
__global__ __launch_bounds__(256) void k_convW(const float* __restrict__ W,
                                               unsigned short* __restrict__ Wt) {
  int tid = blockIdx.x * 256 + threadIdx.x;   // 32768 threads
  int c = tid >> 7, k = tid & 127;
  Wt[tid] = f2bf(W[k * HF + c]);
}

// ---------------------------------------------------------------------------
// K1: operand-swapped MFMA projection GEMM + in-register logits (R8 kernel,
// unchanged). D = Wt(A) x X(B) => lane holds 4 consecutive features of one
// node: direct bf16 stores, no LDS transpose. Logits fp32-exact from acc.
// ---------------------------------------------------------------------------
__global__ __launch_bounds__(256) void k_gemm(const float* __restrict__ X,
                                              const unsigned short* __restrict__ Wt,
                                              const float* __restrict__ att_src,
                                              const float* __restrict__ att_dst,
                                              unsigned short* __restrict__ HhB,
                                              float* __restrict__ AS,
                                              float* __restrict__ AD) {
  __shared__ __align__(16) unsigned short Xs[64 * 136];   // 17408 B
  const int n0 = blockIdx.x * 64;
  const int t = threadIdx.x;

#pragma unroll
  for (int j = 0; j < 8; ++j) {
    int g = t + j * 256;
    int r = g >> 5, c4 = g & 31;
    int gr = n0 + r; if (gr >= NN) gr = NN - 1;
    float4 x = *(const float4*)(X + (size_t)gr * IND + c4 * 4);
    ushort4 u;
    u.x = f2bf(x.x); u.y = f2bf(x.y); u.z = f2bf(x.z); u.w = f2bf(x.w);
    *(ushort4*)(Xs + r * 136 + c4 * 4) = u;
  }
  __syncthreads();

  const int w = t >> 6, lane = t & 63;
  const int quad = lane >> 4, m = lane & 15;
  const int rb = w * 16;
  const int node = n0 + rb + m;

  bfrag xfr[4];
#pragma unroll
  for (int kt = 0; kt < 4; ++kt)
    xfr[kt] = *(const bfrag*)(Xs + (rb + m) * 136 + kt * 32 + quad * 8);

  ffrag acc[16];
#pragma unroll
  for (int ct = 0; ct < 16; ++ct) {
    ffrag c = {0.f, 0.f, 0.f, 0.f};
#pragma unroll
    for (int kt = 0; kt < 4; ++kt) {
      bfrag a = *(const bfrag*)(Wt + (ct * 16 + m) * IND + kt * 32 + quad * 8);
      c = __builtin_amdgcn_mfma_f32_16x16x32_bf16(a, xfr[kt], c, 0, 0, 0);
    }
    acc[ct] = c;
  }

  float ss[8], dd[8];
#pragma unroll
  for (int hh = 0; hh < NH; ++hh) {
    float s = 0.f, d = 0.f;
#pragma unroll
    for (int half = 0; half < 2; ++half) {
      int ct = hh * 2 + half;
      float4 as = *(const float4*)(att_src + ct * 16 + quad * 4);
      float4 ad = *(const float4*)(att_dst + ct * 16 + quad * 4);
      ffrag c = acc[ct];
      s += c[0] * as.x + c[1] * as.y + c[2] * as.z + c[3] * as.w;
      d += c[0] * ad.x + c[1] * ad.y + c[2] * ad.z + c[3] * ad.w;
    }
    s += __shfl_xor(s, 16, 64); s += __shfl_xor(s, 32, 64);
    d += __shfl_xor(d, 16, 64); d += __shfl_xor(d, 32, 64);
    ss[hh] = s; dd[hh] = d;
  }

  if (node < NN) {
#pragma unroll
    for (int ct = 0; ct < 16; ++ct) {
      ushort4 u;
      u.x = f2bf(acc[ct][0]); u.y = f2bf(acc[ct][1]);
      u.z = f2bf(acc[ct][2]); u.w = f2bf(acc[ct][3]);
      *(ushort4*)(HhB + (size_t)node * HF + ct * 16 + quad * 4) = u;
    }
    if (quad == 0) {
      float4 v0 = {ss[0], ss[1], ss[2], ss[3]};
      float4 v1 = {ss[4], ss[5], ss[6], ss[7]};
      *(float4*)(AS + node * NH)     = v0;
      *(float4*)(AS + node * NH + 4) = v1;
      float4 w0 = {dd[0], dd[1], dd[2], dd[3]};
      float4 w1 = {dd[4], dd[5], dd[6], dd[7]};
      *(float4*)(AD + node * NH)     = w0;
      *(float4*)(AD + node * NH + 4) = w1;
    }
  }
}

// ---------------------------------------------------------------------------
// P1: per-block LDS histogram over 782 dst-buckets. No global atomics.
// ghA layout: [blk][NBKT], coalesced block-histogram store.
// ---------------------------------------------------------------------------
__global__ __launch_bounds__(256) void k_p1(const int* __restrict__ ei,
                                            int* __restrict__ ghA) {
  __shared__ int hist[NBKT];
  const int t = threadIdx.x, blk = blockIdx.x;
  for (int b = t; b < NBKT; b += 256) hist[b] = 0;
  __syncthreads();
  const int e0 = blk * EPB;
#pragma unroll 4
  for (int it = 0; it < EPB / 256; ++it) {
    int e = e0 + it * 256 + t;
    if (e < ETOT) {
      int d = (e < NE) ? ei[NE + e] : (e - NE);
      atomicAdd(&hist[d >> 7], 1);
    }
  }
  __syncthreads();
  for (int b = t; b < NBKT; b += 256) ghA[blk * NBKT + b] = hist[b];
}

// ---------------------------------------------------------------------------
// P2: one block. Per-bucket exclusive scan over the NP blocks (in place) +
// exclusive scan of bucket totals -> bktbase[NBKT+1] (bktbase[NBKT]=ETOT).
// ---------------------------------------------------------------------------
__global__ __launch_bounds__(1024) void k_p2(int* __restrict__ ghA,
                                             int* __restrict__ bktbase) {
  __shared__ int sd[1024];
  const int b = threadIdx.x;
  int sum = 0;
  if (b < NBKT) {
    for (int blk = 0; blk < NP; ++blk) {
      int v = ghA[blk * NBKT + b];
      ghA[blk * NBKT + b] = sum;          // exclusive over blocks
      sum += v;
    }
  }
  sd[b] = (b < NBKT) ? sum : 0;
  __syncthreads();
  for (int off = 1; off < 1024; off <<= 1) {
    int x = (b >= off) ? sd[b - off] : 0;
    __syncthreads();
    sd[b] += x;
    __syncthreads();
  }
  if (b < NBKT) bktbase[b] = sd[b] - sum;  // exclusive bucket base
  if (b == NBKT - 1) bktbase[NBKT] = sd[b];  // == ETOT
}

// ---------------------------------------------------------------------------
// P3: partition edges into bucket-grouped part[] (src,dst pairs). Cursors
// live in LDS (init from scanned offsets) -> no global atomics; ~21 edges
// per bucket per block -> ~168-B contiguous write chunks (line-friendly,
// the R2/R8 partial-line lesson).
// ---------------------------------------------------------------------------
__global__ __launch_bounds__(256) void k_p3(const int* __restrict__ ei,
                                            const int* __restrict__ ghA,
                                            const int* __restrict__ bktbase,
                                            uint2* __restrict__ part) {
  __shared__ int curs[NBKT];
  const int t = threadIdx.x, blk = blockIdx.x;
  for (int b = t; b < NBKT; b += 256)
    curs[b] = bktbase[b] + ghA[blk * NBKT + b];
  __syncthreads();
  const int e0 = blk * EPB;
#pragma unroll 4
  for (int it = 0; it < EPB / 256; ++it) {
    int e = e0 + it * 256 + t;
    if (e < ETOT) {
      int s, d;
      if (e < NE) { s = ei[e]; d = ei[NE + e]; } else { s = d = e - NE; }
      int slot = atomicAdd(&curs[d >> 7], 1);
      part[slot] = make_uint2((unsigned)s, (unsigned)d);
    }
  }
}

// ---------------------------------------------------------------------------
// CSRB: one block per bucket. Stage the bucket's pairs in LDS, LDS-hist +
// LDS-scan over the 128 local nodes, coalesced rowptr store, LDS-cursor
// scatter of csr confined to the bucket's hot ~8.7-KB window.
// ---------------------------------------------------------------------------
__global__ __launch_bounds__(256) void k_csrb(const uint2* __restrict__ part,
                                              const int* __restrict__ bktbase,
                                              int* __restrict__ rowptr,
                                              int* __restrict__ csr) {
  __shared__ uint2 pairs[CAP];
  __shared__ int cnt[128], cur[128];
  __shared__ int sd[256];
  const int t = threadIdx.x, b = blockIdx.x;
  const int start = bktbase[b], end = bktbase[b + 1];
  const int m = end - start;
  if (t < 128) cnt[t] = 0;
  __syncthreads();
  const int iters = (m + 255) >> 8;
  for (int it = 0; it < iters; ++it) {
    int i = it * 256 + t;
    if (i < m) {
      uint2 p = part[start + i];
      if (i < CAP) pairs[i] = p;          // CAP overflow: fallback to global
      atomicAdd(&cnt[p.y & 127], 1);
    }
  }
  __syncthreads();
  int v = (t < 128) ? cnt[t] : 0;
  sd[t] = v;
  __syncthreads();
  for (int off = 1; off < 256; off <<= 1) {
    int x = (t >= off) ? sd[t - off] : 0;
    __syncthreads();
    sd[t] += x;
    __syncthreads();
  }
  int lrp = sd[t] - v;                    // exclusive local prefix
  if (t < 128) {
    cur[t] = lrp;
    int node = (b << 7) + t;
    if (node < NN) rowptr[node] = start + lrp;
  }
  if (b == 0 && t == 0) rowptr[NN] = ETOT;
  __syncthreads();
  for (int it = 0; it < iters; ++it) {
    int i = it * 256 + t;
    if (i < m) {
      uint2 p = (i < CAP) ? pairs[i] : part[start + i];
      int slot = atomicAdd(&cur[p.y & 127], 1);
      csr[start + slot] = (int)p.x;
    }
  }
}

// ---------------------------------------------------------------------------
// K3: single-pass GAT aggregation (unchanged — at the delivered-BW wall:
// 870 MB logical gather / 138 us ≈ 6.3 TB/s). One wave per dst node.
// ---------------------------------------------------------------------------
__global__ __launch_bounds__(256) void k_gat(const int* __restrict__ rowptr,
                                             const int* __restrict__ csr,
                                             const float* __restrict__ AS,
                                             const float* __restrict__ AD,
                                             const unsigned short* __restrict__ HhB,
                                             const float* __restrict__ bias,
                                             float* __restrict__ out) {
  const int d = blockIdx.x * 4 + (threadIdx.x >> 6);   // 25000*4 == NN exactly
  const int lane = threadIdx.x & 63;
  const int hh = lane >> 3, sub = lane & 7;
  const int start = rowptr[d], end = rowptr[d + 1];
  const float ad = AD[d * NH + hh];

  float den = 0.f, a0 = 0.f, a1 = 0.f, a2 = 0.f, a3 = 0.f;

  for (int base = start; base < end; base += 64) {
    int srcs = 0;
    if (base + lane < end) srcs = csr[base + lane];
    int m = end - base; if (m > 64) m = 64;
    int t = 0;
    for (; t + 1 < m; t += 2) {               // 2-way unroll for load ILP
      int s0 = __shfl(srcs, t, 64);
      int s1 = __shfl(srcs, t + 1, 64);
      float lg0 = AS[s0 * NH + hh] + ad;
      float lg1 = AS[s1 * NH + hh] + ad;
      ushort4 h0 = *(const ushort4*)(HhB + (size_t)s0 * HF + hh * 32 + sub * 4);
      ushort4 h1 = *(const ushort4*)(HhB + (size_t)s1 * HF + hh * 32 + sub * 4);
      lg0 = lg0 > 0.f ? lg0 : 0.2f * lg0;
      lg1 = lg1 > 0.f ? lg1 : 0.2f * lg1;
      float e0 = __expf(lg0), e1 = __expf(lg1);
      den += e0 + e1;
      a0 += e0 * bf2f(h0.x) + e1 * bf2f(h1.x);
      a1 += e0 * bf2f(h0.y) + e1 * bf2f(h1.y);
      a2 += e0 * bf2f(h0.z) + e1 * bf2f(h1.z);
      a3 += e0 * bf2f(h0.w) + e1 * bf2f(h1.w);
    }
    if (t < m) {
      int s0 = __shfl(srcs, t, 64);
      float lg0 = AS[s0 * NH + hh] + ad;
      ushort4 h0 = *(const ushort4*)(HhB + (size_t)s0 * HF + hh * 32 + sub * 4);
      lg0 = lg0 > 0.f ? lg0 : 0.2f * lg0;
      float e0 = __expf(lg0);
      den += e0;
      a0 += e0 * bf2f(h0.x); a1 += e0 * bf2f(h0.y);
      a2 += e0 * bf2f(h0.z); a3 += e0 * bf2f(h0.w);
    }
  }

  const float inv = 1.f / (den + 1e-16f);
  a0 *= inv; a1 *= inv; a2 *= inv; a3 *= inv;

#pragma unroll
  for (int off = 8; off < 64; off <<= 1) {    // sum over the 8 heads
    a0 += __shfl_xor(a0, off, 64);
    a1 += __shfl_xor(a1, off, 64);
    a2 += __shfl_xor(a2, off, 64);
    a3 += __shfl_xor(a3, off, 64);
  }

  if (lane < 8) {
    float4 o;
    o.x = a0 * 0.125f + bias[sub * 4 + 0];
    o.y = a1 * 0.125f + bias[sub * 4 + 1];
    o.z = a2 * 0.125f + bias[sub * 4 + 2];
    o.w = a3 * 0.125f + bias[sub * 4 + 3];
    *(float4*)(out + (size_t)d * FD + sub * 4) = o;
  }
}

// ---------------------------------------------------------------------------
// Workspace layout:
//   HhB    bf16[N*256]            floats [0,          12,800,000)   51.2 MB
//   AS     float[N*8]                    [12,800,000, 13,600,000)    3.2 MB
//   AD     float[N*8]                    [13,600,000, 14,400,000)    3.2 MB
//   ints (ib = ws + 14,400,000):
//     rowptr  [0,         100,002)
//     csr     [100,002,   1,800,002)
//     ghA     [1,800,002, 1,881,330)   NP x NBKT block histograms
//     bktbase [1,881,330, 1,882,113)
//     Wt      [1,882,114, 1,898,498)   32768 bf16 (W^T)
//     part    [1,898,498, 5,298,498)   uint2[ETOT] (offset even: 8-B aligned)
// ---------------------------------------------------------------------------
extern "C" void kernel_launch(void* const* d_in, const int* in_sizes, int n_in,
                              void* d_out, int out_size, void* d_ws, size_t ws_size,
                              hipStream_t stream) {
  const float* X       = (const float*)d_in[0];
  const int*   ei      = (const int*)d_in[1];
  const float* W       = (const float*)d_in[2];
  const float* att_src = (const float*)d_in[3];
  const float* att_dst = (const float*)d_in[4];
  const float* bias    = (const float*)d_in[5];
  float* out = (float*)d_out;
  float* ws  = (float*)d_ws;

  unsigned short* HhB = (unsigned short*)ws;
  float* AS = ws + 12800000;
  float* AD = ws + 13600000;
  int* ib      = (int*)(ws + 14400000);
  int* rowptr  = ib;
  int* csr     = ib + 100002;
  int* ghA     = ib + 1800002;
  int* bktbase = ib + 1881330;
  unsigned short* Wt = (unsigned short*)(ib + 1882114);
  uint2* part  = (uint2*)(ib + 1898498);

  k_convW<<<128, 256, 0, stream>>>(W, Wt);
  k_gemm <<<GB, 256, 0, stream>>>(X, Wt, att_src, att_dst, HhB, AS, AD);
  k_p1   <<<NP, 256, 0, stream>>>(ei, ghA);
  k_p2   <<<1, 1024, 0, stream>>>(ghA, bktbase);
  k_p3   <<<NP, 256, 0, stream>>>(ei, ghA, bktbase, part);
  k_csrb <<<NBKT, 256, 0, stream>>>(part, bktbase, rowptr, csr);
  k_gat  <<<NN / 4, 256, 0, stream>>>(rowptr, csr, AS, AD, HhB, bias, out);
}

// Round 10
// 386.379 us; speedup vs baseline: 1.1095x; 1.0555x over previous
//
#include <hip/hip_runtime.h>

// Problem constants (fixed by the reference setup)
#define NN 100000          // N_NODES
#define NE 1600000         // N_EDGES
#define IND 128            // IN_DIM
#define FD 32              // OUT_DIM
#define NH 8               // HEADS
#define HF 256             // NH*FD
#define ETOT 1700000       // NE + NN self loops
#define GB 1563            // gemm blocks (ceil(NN/64))

// CSR-build split parameters (LDS-only atomics; R8 lesson)
#define NBKT 782           // dst buckets = ceil(NN/128), bucket = d>>7
#define EPB  16384         // edges per partition block
#define NP   104           // partition blocks = ceil(ETOT/EPB)
#define CAP  3072          // bucket staging capacity (mean 2176, sigma ~46)

typedef __attribute__((ext_vector_type(8))) short bfrag;    // 8 bf16 (4 VGPRs)
typedef __attribute__((ext_vector_type(4))) float ffrag;    // 4 fp32 acc
typedef __attribute__((ext_vector_type(8))) unsigned short us8;

// bf16 helpers (RNE), bit-level to avoid header variance
static __device__ __forceinline__ unsigned short f2bf(float f) {
  union { float f; unsigned u; } v; v.f = f;
  unsigned r = v.u + 0x7FFF + ((v.u >> 16) & 1);
  return (unsigned short)(r >> 16);
}
static __device__ __forceinline__ float bf2f(unsigned short u) {
  union { unsigned u; float f; } v; v.u = ((unsigned)u) << 16;
  return v.f;
}

// ---------------------------------------------------------------------------
// K0: pack W^T in bf16: Wt[c*128 + k] = bf16(W[k*256 + c]).
// ---------------------------------------------------------------------------
__global__ __launch_bounds__(256) void k_convW(const float* __restrict__ W,
                                               unsigned short* __restrict__ Wt) {
  int tid = blockIdx.x * 256 + threadIdx.x;   // 32768 threads
  int c = tid >> 7, k = tid & 127;
  Wt[tid] = f2bf(W[k * HF + c]);
}

// ---------------------------------------------------------------------------
// K1: operand-swapped MFMA GEMM + logits, with (R10) wave-private LDS
// transpose so HhB stores are FULL 128-B lines (R9 post-mortem: the 8-B
// quad-stride stores cost 16 partial-line L2 requests per instruction).
// Blocks >= GB run the dst-bucket histogram (p1) reusing Xs as LDS hist —
// resource-homogeneous fusion (17.4 KB LDS both branches; R7 lesson).
// ---------------------------------------------------------------------------
__global__ __launch_bounds__(256) void k_gemm(const float* __restrict__ X,
                                              const unsigned short* __restrict__ Wt,
                                              const float* __restrict__ att_src,
                                              const float* __restrict__ att_dst,
                                              const int* __restrict__ ei,
                                              unsigned short* __restrict__ HhB,
                                              float* __restrict__ AS,
                                              float* __restrict__ AD,
                                              int* __restrict__ ghA) {
  __shared__ __align__(16) unsigned short Xs[64 * 136];   // 17408 B
  const int t = threadIdx.x;

  if (blockIdx.x >= GB) {          // ---- fused dst-bucket histogram ----
    int* hist = (int*)Xs;          // 782 ints, overlays Xs
    const int blk = blockIdx.x - GB;
    for (int b = t; b < NBKT; b += 256) hist[b] = 0;
    __syncthreads();
    const int e0 = blk * EPB;
#pragma unroll 4
    for (int it = 0; it < EPB / 256; ++it) {
      int e = e0 + it * 256 + t;
      if (e < ETOT) {
        int d = (e < NE) ? ei[NE + e] : (e - NE);
        atomicAdd(&hist[d >> 7], 1);
      }
    }
    __syncthreads();
    for (int b = t; b < NBKT; b += 256) ghA[blk * NBKT + b] = hist[b];
    return;
  }

  // ---- GEMM branch ----
  const int n0 = blockIdx.x * 64;

  // stage X tile fp32 -> bf16 LDS (stride 136 ushorts)
#pragma unroll
  for (int j = 0; j < 8; ++j) {
    int g = t + j * 256;
    int r = g >> 5, c4 = g & 31;
    int gr = n0 + r; if (gr >= NN) gr = NN - 1;
    float4 x = *(const float4*)(X + (size_t)gr * IND + c4 * 4);
    ushort4 u;
    u.x = f2bf(x.x); u.y = f2bf(x.y); u.z = f2bf(x.z); u.w = f2bf(x.w);
    *(ushort4*)(Xs + r * 136 + c4 * 4) = u;
  }
  __syncthreads();

  const int w = t >> 6, lane = t & 63;
  const int quad = lane >> 4, m = lane & 15;
  const int rb = w * 16;
  const int node = n0 + rb + m;

  // B operand: X fragment (wave-private rows rb..rb+15)
  bfrag xfr[4];
#pragma unroll
  for (int kt = 0; kt < 4; ++kt)
    xfr[kt] = *(const bfrag*)(Xs + (rb + m) * 136 + kt * 32 + quad * 8);

  ffrag acc[16];
#pragma unroll
  for (int ct = 0; ct < 16; ++ct) {
    ffrag c = {0.f, 0.f, 0.f, 0.f};
#pragma unroll
    for (int kt = 0; kt < 4; ++kt) {
      bfrag a = *(const bfrag*)(Wt + (ct * 16 + m) * IND + kt * 32 + quad * 8);
      c = __builtin_amdgcn_mfma_f32_16x16x32_bf16(a, xfr[kt], c, 0, 0, 0);
    }
    acc[ct] = c;
  }

  // logits from fp32 accumulators (exact)
  float ss[8], dd[8];
#pragma unroll
  for (int hh = 0; hh < NH; ++hh) {
    float s = 0.f, d = 0.f;
#pragma unroll
    for (int half = 0; half < 2; ++half) {
      int ct = hh * 2 + half;
      float4 as = *(const float4*)(att_src + ct * 16 + quad * 4);
      float4 ad = *(const float4*)(att_dst + ct * 16 + quad * 4);
      ffrag c = acc[ct];
      s += c[0] * as.x + c[1] * as.y + c[2] * as.z + c[3] * as.w;
      d += c[0] * ad.x + c[1] * ad.y + c[2] * ad.z + c[3] * ad.w;
    }
    s += __shfl_xor(s, 16, 64); s += __shfl_xor(s, 32, 64);
    d += __shfl_xor(d, 16, 64); d += __shfl_xor(d, 32, 64);
    ss[hh] = s; dd[hh] = d;
  }
  if (quad == 0 && node < NN) {
    float4 v0 = {ss[0], ss[1], ss[2], ss[3]};
    float4 v1 = {ss[4], ss[5], ss[6], ss[7]};
    *(float4*)(AS + node * NH)     = v0;
    *(float4*)(AS + node * NH + 4) = v1;
    float4 w0 = {dd[0], dd[1], dd[2], dd[3]};
    float4 w1 = {dd[4], dd[5], dd[6], dd[7]};
    *(float4*)(AD + node * NH)     = w0;
    *(float4*)(AD + node * NH + 4) = w1;
  }

  // wave-private transpose: 2 passes of 128 feats through rows rb..rb+15.
  // Readout: 8 lanes cover one row's 128-B line -> fully-coalesced stores.
#pragma unroll
  for (int pass = 0; pass < 2; ++pass) {
#pragma unroll
    for (int c8 = 0; c8 < 8; ++c8) {
      int ct = pass * 8 + c8;
      ushort4 u;
      u.x = f2bf(acc[ct][0]); u.y = f2bf(acc[ct][1]);
      u.z = f2bf(acc[ct][2]); u.w = f2bf(acc[ct][3]);
      *(ushort4*)(Xs + (rb + m) * 136 + c8 * 16 + quad * 4) = u;
    }
    __syncthreads();
#pragma unroll
    for (int jj = 0; jj < 2; ++jj)
#pragma unroll
      for (int kk = 0; kk < 2; ++kk) {
        int rl = (lane >> 3) + 8 * jj;          // 0..15
        int c = lane & 7;
        int node2 = n0 + rb + rl;
        us8 v = *(const us8*)(Xs + (rb + rl) * 136 + kk * 64 + c * 8);
        if (node2 < NN)
          *(us8*)(HhB + (size_t)node2 * HF + pass * 128 + kk * 64 + c * 8) = v;
      }
    __syncthreads();
  }
}

// ---------------------------------------------------------------------------
// P2: one block. Per-bucket exclusive scan over the NP blocks (in place) +
// exclusive scan of bucket totals -> bktbase[NBKT+1].
// ---------------------------------------------------------------------------
__global__ __launch_bounds__(1024) void k_p2(int* __restrict__ ghA,
                                             int* __restrict__ bktbase) {
  __shared__ int sd[1024];
  const int b = threadIdx.x;
  int sum = 0;
  if (b < NBKT) {
    for (int blk = 0; blk < NP; ++blk) {
      int v = ghA[blk * NBKT + b];
      ghA[blk * NBKT + b] = sum;
      sum += v;
    }
  }
  sd[b] = (b < NBKT) ? sum : 0;
  __syncthreads();
  for (int off = 1; off < 1024; off <<= 1) {
    int x = (b >= off) ? sd[b - off] : 0;
    __syncthreads();
    sd[b] += x;
    __syncthreads();
  }
  if (b < NBKT) bktbase[b] = sd[b] - sum;
  if (b == NBKT - 1) bktbase[NBKT] = sd[b];
}

// ---------------------------------------------------------------------------
// P3: partition edges into bucket-grouped part[] — 32-bit packed record
// (s<<7 | d&127): halves write traffic vs uint2. LDS cursors, no global
// atomics; ~21 edges/bucket/block -> contiguous chunks (R2 lesson).
// ---------------------------------------------------------------------------
__global__ __launch_bounds__(256) void k_p3(const int* __restrict__ ei,
                                            const int* __restrict__ ghA,
                                            const int* __restrict__ bktbase,
                                            unsigned* __restrict__ part) {
  __shared__ int curs[NBKT];
  const int t = threadIdx.x, blk = blockIdx.x;
  for (int b = t; b < NBKT; b += 256)
    curs[b] = bktbase[b] + ghA[blk * NBKT + b];
  __syncthreads();
  const int e0 = blk * EPB;
#pragma unroll 4
  for (int it = 0; it < EPB / 256; ++it) {
    int e = e0 + it * 256 + t;
    if (e < ETOT) {
      int s, d;
      if (e < NE) { s = ei[e]; d = ei[NE + e]; } else { s = d = e - NE; }
      int slot = atomicAdd(&curs[d >> 7], 1);
      part[slot] = ((unsigned)s << 7) | (unsigned)(d & 127);
    }
  }
}

// ---------------------------------------------------------------------------
// CSRB: one block per bucket. Stage packed pairs in LDS, LDS-hist +
// LDS-scan over 128 local nodes, coalesced rowptr store, LDS-cursor
// scatter of csr confined to the bucket's hot window.
// ---------------------------------------------------------------------------
__global__ __launch_bounds__(256) void k_csrb(const unsigned* __restrict__ part,
                                              const int* __restrict__ bktbase,
                                              int* __restrict__ rowptr,
                                              int* __restrict__ csr) {
  __shared__ unsigned pairs[CAP];
  __shared__ int cnt[128], cur[128];
  __shared__ int sd[256];
  const int t = threadIdx.x, b = blockIdx.x;
  const int start = bktbase[b], end = bktbase[b + 1];
  const int m = end - start;
  if (t < 128) cnt[t] = 0;
  __syncthreads();
  const int iters = (m + 255) >> 8;
  for (int it = 0; it < iters; ++it) {
    int i = it * 256 + t;
    if (i < m) {
      unsigned p = part[start + i];
      if (i < CAP) pairs[i] = p;          // CAP overflow: fallback to global
      atomicAdd(&cnt[p & 127], 1);
    }
  }
  __syncthreads();
  int v = (t < 128) ? cnt[t] : 0;
  sd[t] = v;
  __syncthreads();
  for (int off = 1; off < 256; off <<= 1) {
    int x = (t >= off) ? sd[t - off] : 0;
    __syncthreads();
    sd[t] += x;
    __syncthreads();
  }
  int lrp = sd[t] - v;
  if (t < 128) {
    cur[t] = lrp;
    int node = (b << 7) + t;
    if (node < NN) rowptr[node] = start + lrp;
  }
  if (b == 0 && t == 0) rowptr[NN] = ETOT;
  __syncthreads();
  for (int it = 0; it < iters; ++it) {
    int i = it * 256 + t;
    if (i < m) {
      unsigned p = (i < CAP) ? pairs[i] : part[start + i];
      int slot = atomicAdd(&cur[p & 127], 1);
      csr[start + slot] = (int)(p >> 7);
    }
  }
}

// ---------------------------------------------------------------------------
// K3: single-pass GAT aggregation (unchanged — at the delivered-BW wall:
// 870 MB logical gather / 138 us ≈ 6.3 TB/s). One wave per dst node.
// ---------------------------------------------------------------------------
__global__ __launch_bounds__(256) void k_gat(const int* __restrict__ rowptr,
                                             const int* __restrict__ csr,
                                             const float* __restrict__ AS,
                                             const float* __restrict__ AD,
                                             const unsigned short* __restrict__ HhB,
                                             const float* __restrict__ bias,
                                             float* __restrict__ out) {
  const int d = blockIdx.x * 4 + (threadIdx.x >> 6);   // 25000*4 == NN exactly
  const int lane = threadIdx.x & 63;
  const int hh = lane >> 3, sub = lane & 7;
  const int start = rowptr[d], end = rowptr[d + 1];
  const float ad = AD[d * NH + hh];

  float den = 0.f, a0 = 0.f, a1 = 0.f, a2 = 0.f, a3 = 0.f;

  for (int base = start; base < end; base += 64) {
    int srcs = 0;
    if (base + lane < end) srcs = csr[base + lane];
    int m = end - base; if (m > 64) m = 64;
    int t = 0;
    for (; t + 1 < m; t += 2) {               // 2-way unroll for load ILP
      int s0 = __shfl(srcs, t, 64);
      int s1 = __shfl(srcs, t + 1, 64);
      float lg0 = AS[s0 * NH + hh] + ad;
      float lg1 = AS[s1 * NH + hh] + ad;
      ushort4 h0 = *(const ushort4*)(HhB + (size_t)s0 * HF + hh * 32 + sub * 4);
      ushort4 h1 = *(const ushort4*)(HhB + (size_t)s1 * HF + hh * 32 + sub * 4);
      lg0 = lg0 > 0.f ? lg0 : 0.2f * lg0;
      lg1 = lg1 > 0.f ? lg1 : 0.2f * lg1;
      float e0 = __expf(lg0), e1 = __expf(lg1);
      den += e0 + e1;
      a0 += e0 * bf2f(h0.x) + e1 * bf2f(h1.x);
      a1 += e0 * bf2f(h0.y) + e1 * bf2f(h1.y);
      a2 += e0 * bf2f(h0.z) + e1 * bf2f(h1.z);
      a3 += e0 * bf2f(h0.w) + e1 * bf2f(h1.w);
    }
    if (t < m) {
      int s0 = __shfl(srcs, t, 64);
      float lg0 = AS[s0 * NH + hh] + ad;
      ushort4 h0 = *(const ushort4*)(HhB + (size_t)s0 * HF + hh * 32 + sub * 4);
      lg0 = lg0 > 0.f ? lg0 : 0.2f * lg0;
      float e0 = __expf(lg0);
      den += e0;
      a0 += e0 * bf2f(h0.x); a1 += e0 * bf2f(h0.y);
      a2 += e0 * bf2f(h0.z); a3 += e0 * bf2f(h0.w);
    }
  }

  const float inv = 1.f / (den + 1e-16f);
  a0 *= inv; a1 *= inv; a2 *= inv; a3 *= inv;

#pragma unroll
  for (int off = 8; off < 64; off <<= 1) {    // sum over the 8 heads
    a0 += __shfl_xor(a0, off, 64);
    a1 += __shfl_xor(a1, off, 64);
    a2 += __shfl_xor(a2, off, 64);
    a3 += __shfl_xor(a3, off, 64);
  }

  if (lane < 8) {
    float4 o;
    o.x = a0 * 0.125f + bias[sub * 4 + 0];
    o.y = a1 * 0.125f + bias[sub * 4 + 1];
    o.z = a2 * 0.125f + bias[sub * 4 + 2];
    o.w = a3 * 0.125f + bias[sub * 4 + 3];
    *(float4*)(out + (size_t)d * FD + sub * 4) = o;
  }
}

// ---------------------------------------------------------------------------
// Workspace layout:
//   HhB    bf16[N*256]            floats [0,          12,800,000)   51.2 MB
//   AS     float[N*8]                    [12,800,000, 13,600,000)    3.2 MB
//   AD     float[N*8]                    [13,600,000, 14,400,000)    3.2 MB
//   ints (ib = ws + 14,400,000):
//     rowptr  [0,         100,002)
//     csr     [100,002,   1,800,002)
//     ghA     [1,800,002, 1,881,330)   NP x NBKT block histograms
//     bktbase [1,881,330, 1,882,113)
//     Wt      [1,882,114, 1,898,498)   32768 bf16 (W^T)
//     part    [1,898,498, 3,598,498)   packed unsigned[ETOT]
// ---------------------------------------------------------------------------
extern "C" void kernel_launch(void* const* d_in, const int* in_sizes, int n_in,
                              void* d_out, int out_size, void* d_ws, size_t ws_size,
                              hipStream_t stream) {
  const float* X       = (const float*)d_in[0];
  const int*   ei      = (const int*)d_in[1];
  const float* W       = (const float*)d_in[2];
  const float* att_src = (const float*)d_in[3];
  const float* att_dst = (const float*)d_in[4];
  const float* bias    = (const float*)d_in[5];
  float* out = (float*)d_out;
  float* ws  = (float*)d_ws;

  unsigned short* HhB = (unsigned short*)ws;
  float* AS = ws + 12800000;
  float* AD = ws + 13600000;
  int* ib      = (int*)(ws + 14400000);
  int* rowptr  = ib;
  int* csr     = ib + 100002;
  int* ghA     = ib + 1800002;
  int* bktbase = ib + 1881330;
  unsigned short* Wt = (unsigned short*)(ib + 1882114);
  unsigned* part = (unsigned*)(ib + 1898498);

  k_convW<<<128, 256, 0, stream>>>(W, Wt);
  k_gemm <<<GB + NP, 256, 0, stream>>>(X, Wt, att_src, att_dst, ei,
                                       HhB, AS, AD, ghA);
  k_p2   <<<1, 1024, 0, stream>>>(ghA, bktbase);
  k_p3   <<<NP, 256, 0, stream>>>(ei, ghA, bktbase, part);
  k_csrb <<<NBKT, 256, 0, stream>>>(part, bktbase, rowptr, csr);
  k_gat  <<<NN / 4, 256, 0, stream>>>(rowptr, csr, AS, AD, HhB, bias, out);
}